// Round 4
// baseline (421.129 us; speedup 1.0000x reference)
//
#include <hip/hip_runtime.h>

// Causal attention head: B=4, T=2048, C=1024, fp32 in/out.
//   k = x@Wk^T, q = x@Wq^T, v = x@Wv^T ; S = q@k^T (no scale, causal) ;
//   P = softmax(S) ; out = P@v
//
// R4 (counter-driven): all GEMMs -> 8-wave 256x128 tile, BK=64, double-buffered
// LDS (96 KiB), counted s_waitcnt vmcnt(6) across raw s_barrier (T4: never
// drain to 0 in steady state), setprio around MFMA (T5), XOR-swizzled LDS via
// pre-swizzled global source (T2, proven R2: conflicts=0), XCD swizzle (T1).
// Pipeline per K-step kt:
//   compute(buf[kt&1])            // reads current buffer
//   s_barrier                     // all waves done reading buf[cur]
//   STAGE(buf[cur] <- kt+2)       // overwrite is now safe
//   s_waitcnt vmcnt(6)            // waits ONLY kt+1's 6 loads (12 in flight)
//   s_barrier                     // kt+1 visible to all waves
// Numerics identical to R3 (absmax 0.015625): q/k split-bf16 3-pass, v 1-pass,
// S fp32, P bf16.
//
// Workspace layout (byte offsets; lifetime overlays; 151 MiB used):
//   [0,        67108864)  S fp32 [4][2048][2048]   (written AFTER W+x are dead)
//     [0,      12582912)   W splits: wkhi,wklo,wqhi,wqlo,wvhi,wvlo (2 MiB each)
//     [12582912,46137344)  xhi, xlo (16 MiB each)
//   [67108864, 134217728) qhi,qlo,khi,klo (16 MiB each)
//     [67108864,100663296) P bf16 [4][2048][2048]  (overlays q after S-GEMM)
//   [134217728,150994944) vthi [4][1024][2048] (16 MiB)

#define GLOBAL_AS __attribute__((address_space(1)))
#define LDS_AS    __attribute__((address_space(3)))

typedef __attribute__((ext_vector_type(8))) short short8;
typedef __attribute__((ext_vector_type(4))) float f32x4;
typedef long long ll;

__device__ __forceinline__ unsigned short f2bf(float f) {
  unsigned u = __float_as_uint(f);
  u += 0x7FFFu + ((u >> 16) & 1u);   // RTNE (finite values only here)
  return (unsigned short)(u >> 16);
}
__device__ __forceinline__ float bf2f(unsigned short s) {
  return __uint_as_float((unsigned)s << 16);
}

__device__ __forceinline__ void gload_lds16(const unsigned short* g, unsigned short* l) {
  __builtin_amdgcn_global_load_lds((const GLOBAL_AS unsigned int*)g,
                                   (LDS_AS unsigned int*)l, 16, 0, 0);
}

// ---------------- fp32 -> (bf16 hi, bf16 lo) split conversion -----------------
__global__ __launch_bounds__(256) void split_f32_kernel(
    const float* __restrict__ src, unsigned short* __restrict__ hi,
    unsigned short* __restrict__ lo, int n8) {
  int i = blockIdx.x * 256 + threadIdx.x;
  if (i >= n8) return;
  const float4* s4 = (const float4*)src;
  float4 a = s4[2 * i], c = s4[2 * i + 1];
  float v[8] = {a.x, a.y, a.z, a.w, c.x, c.y, c.z, c.w};
  unsigned hw[4], lw[4];
#pragma unroll
  for (int j = 0; j < 4; ++j) {
    unsigned short h0 = f2bf(v[2 * j]),     h1 = f2bf(v[2 * j + 1]);
    unsigned short l0 = f2bf(v[2 * j] - bf2f(h0));
    unsigned short l1 = f2bf(v[2 * j + 1] - bf2f(h1));
    hw[j] = (unsigned)h0 | ((unsigned)h1 << 16);
    lw[j] = (unsigned)l0 | ((unsigned)l1 << 16);
  }
  *(uint4*)(hi + 8 * i) = make_uint4(hw[0], hw[1], hw[2], hw[3]);
  *(uint4*)(lo + 8 * i) = make_uint4(lw[0], lw[1], lw[2], lw[3]);
}

// ---------- 8-wave 256x128 A·B^T GEMM, dbuf + counted-vmcnt pipeline ----------
// 512 thr = 8 waves (2M x 4N is folded as wm=w>>1 in [0,4), wn=w&1): per-wave
// 64x64 output = 4x4 frags of 16x16. A-tile 256x64 (4 loads/thr), B-tile
// 128x64 (2 loads/thr). LDS data swizzled: 16B chunk j of row r at slot
// j^(r&7), via pre-swizzled global source + XOR on ds_read (rule #21).
// K-virtual streams: kb -> pass p=kb>>4 (0:hh 1:hl 2:lh), k0=(kb&15)*64.
// MODE 0 = fused qkv proj (grid.x=32*24; tj>>3 picks q/k/v; v: 1 pass ->vT)
// MODE 1 = S=q k^T causal (grid.x=72: tiles tj<=2ti+1; 3 passes; fp32 out)
// MODE 2 = out=P vT^T (grid.x=64; 1 pass; kEnd=(ti+1)*256; fp32 out)
template <int MODE>
__global__ __launch_bounds__(512, 2) void gemm8w(
    const unsigned short* __restrict__ A0, const unsigned short* __restrict__ A1,
    int lda, ll strA,
    const unsigned short* __restrict__ B0, const unsigned short* __restrict__ B1,
    const unsigned short* __restrict__ B2, const unsigned short* __restrict__ B3,
    const unsigned short* __restrict__ B4,
    int ldb, ll strB,
    void* __restrict__ C0, void* __restrict__ C1, void* __restrict__ C2,
    void* __restrict__ C3, void* __restrict__ C4, int ldc, ll strC, int ntc) {
  // 96 KiB: A bufs [2][16384] shorts | B bufs [2][8192] shorts
  __shared__ __align__(16) unsigned short smem[49152];

  // T1: XCD-chunked swizzle (grid.x % 8 == 0 for all launches)
  const int bx0 = blockIdx.x;
  const int bx = (bx0 & 7) * (gridDim.x >> 3) + (bx0 >> 3);
  const int b = blockIdx.y;
  int ti, tj;
  if constexpr (MODE == 1) {  // causal: row-tile ti has 2(ti+1) col-tiles
    int rem = bx, i = 0;
    while (rem >= 2 * (i + 1)) { rem -= 2 * (i + 1); ++i; }
    ti = i; tj = rem;
  } else {
    ti = bx / ntc; tj = bx - ti * ntc;
  }
  const int row0 = ti << 8;

  const unsigned short *aH, *aL, *bH, *bL;
  int nkb, which = 0, colw = 0;
  if constexpr (MODE == 0) {
    which = tj >> 3; colw = (tj & 7) << 7;
    aH = A0 + (ll)row0 * lda; aL = A1 + (ll)row0 * lda;
    if (which == 0)      { bH = B0; bL = B1; }
    else if (which == 1) { bH = B2; bL = B3; }
    else                 { bH = B4; bL = B4; }
    bH += (ll)colw * ldb; bL += (ll)colw * ldb;
    nkb = (which == 2) ? 16 : 48;
  } else if constexpr (MODE == 1) {
    aH = A0 + (ll)b * strA + (ll)row0 * lda; aL = A1 + (ll)b * strA + (ll)row0 * lda;
    bH = B0 + (ll)b * strB + (ll)(tj << 7) * ldb; bL = B1 + (ll)b * strB + (ll)(tj << 7) * ldb;
    nkb = 48;
  } else {
    aH = A0 + (ll)b * strA + (ll)row0 * lda; aL = aH;
    bH = B0 + (ll)b * strB + (ll)(tj << 7) * ldb; bL = bH;
    nkb = (ti + 1) << 2;
  }

  const int t = threadIdx.x;
  const int lane = t & 63, w = t >> 6;
  const int wm = w >> 1, wn = w & 1;
  const int fr = lane & 15, fg = lane >> 4;

  // staging maps (fixed per thread; +k0 at issue). Source chunk XOR-swizzled.
  ll aoff[4]; int adst[4];
#pragma unroll
  for (int c = 0; c < 4; ++c) {
    const int lin = c * 512 + t, r = lin >> 3, j = lin & 7;
    aoff[c] = (ll)r * lda + ((j ^ (r & 7)) << 3);
    adst[c] = lin << 3;
  }
  ll boff[2]; int bdst[2];
#pragma unroll
  for (int c = 0; c < 2; ++c) {
    const int lin = c * 512 + t, r = lin >> 3, j = lin & 7;
    boff[c] = (ll)r * ldb + ((j ^ (r & 7)) << 3);
    bdst[c] = lin << 3;
  }
  // ds_read maps (de-swizzle on read)
  int offA[4][2], offB[4][2];
#pragma unroll
  for (int m = 0; m < 4; ++m) {
    const int row = wm * 64 + m * 16 + fr;
#pragma unroll
    for (int ks = 0; ks < 2; ++ks)
      offA[m][ks] = row * 64 + (((ks * 4 + fg) ^ (row & 7)) << 3);
  }
#pragma unroll
  for (int n = 0; n < 4; ++n) {
    const int row = wn * 64 + n * 16 + fr;
#pragma unroll
    for (int ks = 0; ks < 2; ++ks)
      offB[n][ks] = row * 64 + (((ks * 4 + fg) ^ (row & 7)) << 3);
  }

  auto STAGE = [&](int buf, int kb) {
    int p, k0;
    if constexpr (MODE == 2) { p = 0; k0 = kb << 6; }
    else                     { p = kb >> 4; k0 = (kb & 15) << 6; }
    const unsigned short* pA = (p == 2) ? aL : aH;
    const unsigned short* pB = (p == 1) ? bL : bH;
    unsigned short* LA = smem + buf * 16384;
    unsigned short* LB = smem + 32768 + buf * 8192;
#pragma unroll
    for (int c = 0; c < 4; ++c) gload_lds16(pA + aoff[c] + k0, LA + adst[c]);
#pragma unroll
    for (int c = 0; c < 2; ++c) gload_lds16(pB + boff[c] + k0, LB + bdst[c]);
  };

  f32x4 acc[4][4];
#pragma unroll
  for (int m = 0; m < 4; ++m)
#pragma unroll
    for (int n = 0; n < 4; ++n) acc[m][n] = (f32x4){0.f, 0.f, 0.f, 0.f};

  // ---- prologue: 2 buffers in flight; wait only buf0 (nkb >= 4 always) ----
  STAGE(0, 0);
  STAGE(1, 1);
  asm volatile("s_waitcnt vmcnt(6)" ::: "memory");
  __builtin_amdgcn_s_barrier();

  for (int kt = 0; kt < nkb; ++kt) {
    const int cur = kt & 1;
    const unsigned short* LA = smem + cur * 16384;
    const unsigned short* LB = smem + 32768 + cur * 8192;
    asm volatile("" ::: "memory");
#pragma unroll
    for (int ks = 0; ks < 2; ++ks) {
      short8 a[4], bb[4];
#pragma unroll
      for (int m = 0; m < 4; ++m) a[m] = *(const short8*)(LA + offA[m][ks]);
#pragma unroll
      for (int n = 0; n < 4; ++n) bb[n] = *(const short8*)(LB + offB[n][ks]);
      __builtin_amdgcn_s_setprio(1);
#pragma unroll
      for (int n = 0; n < 4; ++n)
#pragma unroll
        for (int m = 0; m < 4; ++m)
          acc[m][n] = __builtin_amdgcn_mfma_f32_16x16x32_bf16(a[m], bb[n], acc[m][n], 0, 0, 0);
      __builtin_amdgcn_s_setprio(0);
    }
    asm volatile("" ::: "memory");
    __builtin_amdgcn_s_barrier();          // all waves done reading buf[cur]
    if (kt + 2 < nkb) {
      STAGE(cur, kt + 2);                  // safe: everyone past reads of cur
      asm volatile("s_waitcnt vmcnt(6)" ::: "memory");  // kt+1 landed (ours)
    } else {
      asm volatile("s_waitcnt vmcnt(0)" ::: "memory");  // tail drain
    }
    __builtin_amdgcn_s_barrier();          // kt+1 landed for ALL waves
  }

  // ---- epilogue: D layout col=lane&15, row=(lane>>4)*4+j [m89-verified] ----
#pragma unroll
  for (int m = 0; m < 4; ++m)
#pragma unroll
    for (int n = 0; n < 4; ++n)
#pragma unroll
      for (int j = 0; j < 4; ++j) {
        const int r = row0 + wm * 64 + m * 16 + fg * 4 + j;
        const int cl = wn * 64 + n * 16 + fr;
        const float v = acc[m][n][j];
        if constexpr (MODE == 0) {
          if (which == 2) {  // vT[b][d][t] bf16
            const int bb2 = r >> 11, tt = r & 2047;
            ((unsigned short*)C4)[(ll)bb2 * (1024LL * 2048) + (ll)(colw + cl) * 2048 + tt] = f2bf(v);
          } else {           // split bf16 q or k
            unsigned short* hi = (unsigned short*)(which == 0 ? C0 : C2);
            unsigned short* lo = (unsigned short*)(which == 0 ? C1 : C3);
            const ll addr = (ll)r * 1024 + colw + cl;
            const unsigned short h = f2bf(v);
            hi[addr] = h;
            lo[addr] = f2bf(v - bf2f(h));
          }
        } else {  // fp32 C0[b*strC + r*ldc + col0+cl]
          ((float*)C0)[(ll)b * strC + (ll)r * ldc + ((tj << 7) + cl)] = v;
        }
      }
}

// ---------------- causal row softmax: S fp32 -> P bf16 (zero-filled) ----------
__global__ __launch_bounds__(256) void softmax_causal_kernel(
    const float* __restrict__ S, unsigned short* __restrict__ P) {
  __shared__ float red[8];
  const int tq = blockIdx.x;  // row 0..2047
  const int b = blockIdx.y;
  const float* s = S + (ll)b * 2048 * 2048 + (ll)tq * 2048;
  unsigned short* p = P + (ll)b * 2048 * 2048 + (ll)tq * 2048;
  const int n = tq + 1;  // valid cols
  const int t = threadIdx.x;

  float vals[8];
  float mx = -1e30f;
#pragma unroll
  for (int c = 0; c < 8; ++c) {
    const int i = t + c * 256;
    if (i < n) { vals[c] = s[i]; mx = fmaxf(mx, vals[c]); }
  }
#pragma unroll
  for (int o = 32; o > 0; o >>= 1) mx = fmaxf(mx, __shfl_xor(mx, o, 64));
  if ((t & 63) == 0) red[t >> 6] = mx;
  __syncthreads();
  mx = fmaxf(fmaxf(red[0], red[1]), fmaxf(red[2], red[3]));

  float sum = 0.f;
#pragma unroll
  for (int c = 0; c < 8; ++c) {
    const int i = t + c * 256;
    if (i < n) { const float e = __expf(vals[c] - mx); vals[c] = e; sum += e; }
  }
#pragma unroll
  for (int o = 32; o > 0; o >>= 1) sum += __shfl_xor(sum, o, 64);
  if ((t & 63) == 0) red[4 + (t >> 6)] = sum;
  __syncthreads();
  sum = (red[4] + red[5]) + (red[6] + red[7]);
  const float inv = 1.0f / sum;
#pragma unroll
  for (int c = 0; c < 8; ++c) {
    const int i = t + c * 256;
    if (i < n) p[i] = f2bf(vals[c] * inv);
  }
  for (int ii = t; ii < 2048; ii += 256)
    if (ii >= n) p[ii] = 0;  // zero-fill masked cols so PV reads are clean
}

// -------------------------------- launch --------------------------------------
extern "C" void kernel_launch(void* const* d_in, const int* in_sizes, int n_in,
                              void* d_out, int out_size, void* d_ws, size_t ws_size,
                              hipStream_t stream) {
  (void)in_sizes; (void)n_in; (void)out_size; (void)ws_size;
  const float* x  = (const float*)d_in[0];
  const float* Wk = (const float*)d_in[1];  // input order: x, Wk, Wq, Wv
  const float* Wq = (const float*)d_in[2];
  const float* Wv = (const float*)d_in[3];
  char* ws = (char*)d_ws;

  float*          Sbuf = (float*)ws;                              // 64 MiB
  unsigned short* wkhi = (unsigned short*)(ws + 0);
  unsigned short* wklo = (unsigned short*)(ws + 2097152);
  unsigned short* wqhi = (unsigned short*)(ws + 4194304);
  unsigned short* wqlo = (unsigned short*)(ws + 6291456);
  unsigned short* wvhi = (unsigned short*)(ws + 8388608);
  unsigned short* wvlo = (unsigned short*)(ws + 10485760);
  unsigned short* xhi  = (unsigned short*)(ws + 12582912);
  unsigned short* xlo  = (unsigned short*)(ws + 29360128);
  unsigned short* qhi  = (unsigned short*)(ws + 67108864);
  unsigned short* qlo  = (unsigned short*)(ws + 83886080);
  unsigned short* khi  = (unsigned short*)(ws + 100663296);
  unsigned short* klo  = (unsigned short*)(ws + 117440512);
  unsigned short* Pbuf = (unsigned short*)(ws + 67108864);        // overlays q
  unsigned short* vthi = (unsigned short*)(ws + 134217728);

  // 1) split conversions (Wv lo converted but unused)
  split_f32_kernel<<<4096, 256, 0, stream>>>(x, xhi, xlo, 1048576);
  split_f32_kernel<<<512, 256, 0, stream>>>(Wq, wqhi, wqlo, 131072);
  split_f32_kernel<<<512, 256, 0, stream>>>(Wk, wkhi, wklo, 131072);
  split_f32_kernel<<<512, 256, 0, stream>>>(Wv, wvhi, wvlo, 131072);

  // 2) fused qkv projection: 32 row-tiles x 24 col-tiles (8 q | 8 k | 8 v)
  gemm8w<0><<<dim3(768, 1), 512, 0, stream>>>(
      xhi, xlo, 1024, 0,
      wqhi, wqlo, wkhi, wklo, wvhi, 1024, 0,
      qhi, qlo, khi, klo, vthi, 1024, 0, 24);

  // 3) S = q k^T, causal 256x128 tiles: 72 tiles x 4 batches
  gemm8w<1><<<dim3(72, 4), 512, 0, stream>>>(
      qhi, qlo, 1024, 2048LL * 1024,
      khi, klo, nullptr, nullptr, nullptr, 1024, 2048LL * 1024,
      Sbuf, nullptr, nullptr, nullptr, nullptr, 2048, 2048LL * 2048, 8);

  // 4) causal softmax -> P (bf16, zero-filled above diagonal)
  softmax_causal_kernel<<<dim3(2048, 4), 256, 0, stream>>>(Sbuf, Pbuf);

  // 5) out = P vT^T: 8 row-tiles x 8 col-tiles, kEnd=(ti+1)*256
  gemm8w<2><<<dim3(64, 4), 512, 0, stream>>>(
      Pbuf, nullptr, 2048, 2048LL * 2048,
      vthi, nullptr, nullptr, nullptr, nullptr, 2048, 1024LL * 2048,
      d_out, nullptr, nullptr, nullptr, nullptr, 1024, 2048LL * 1024, 8);
}

// Round 5
// 396.339 us; speedup vs baseline: 1.0625x; 1.0625x over previous
//
#include <hip/hip_runtime.h>

// Causal attention head: B=4, T=2048, C=1024, fp32 in/out.
//   k = x@Wk^T, q = x@Wq^T, v = x@Wv^T ; S = q@k^T (no scale, causal) ;
//   P = softmax(S) ; out = P@v
//
// R5: true m201-geometry 8-phase GEMM template (plain HIP):
//   BM=BN=256, BK=64, 512 thr = 8 waves (2M x 4N), per-wave 128x64 output
//   (8x4 frags of 16x16), LDS 128 KiB double-buffered (A 2x32KB, B 2x32KB).
//   Per K-tile: 4 phases {ds_read subtile; stage-issue; s_barrier; setprio(1);
//   16 MFMA; setprio(0); s_barrier}. Phase 0 reads all 8 B-frags (register
//   subtile, cached whole K-tile) + A quadrant 0 (12 reads); phases 1-3 read
//   A quadrants (4 reads each). Staging: A(j+1) issued @p0 (overwrites A(j-1),
//   read-complete at j-1 p3+barrier), B(j+2) @p1/p2 (overwrites B(j),
//   read-complete at p0+barrier). ONE counted vmcnt(4) per K-tile at p3:
//   waits A(j+1)+B(j+1) landed, leaves B(j+2)'s 4 loads in flight (T4: never
//   0 in steady state). T2 XOR-swizzle (R2-proven, conflicts=0), T5 setprio,
//   m204 bijective XCD swizzle.
// Numerics identical to R3/R4 (absmax 0.015625): q/k split-bf16 3-pass
// (K-virtualized: kb -> pass p=kb>>4 in {hh,hl,lh}), v 1-pass, S fp32, P bf16.
//
// Workspace layout (byte offsets; lifetime overlays; 151 MiB used):
//   [0,        67108864)  S fp32 [4][2048][2048]   (written AFTER W+x dead)
//     [0,      12582912)   W splits: wkhi,wklo,wqhi,wqlo,wvhi,wvlo (2 MiB each)
//     [12582912,46137344)  xhi, xlo (16 MiB each)
//   [67108864, 134217728) qhi,qlo,khi,klo (16 MiB each)
//     [67108864,100663296) P bf16 [4][2048][2048]  (overlays q after S-GEMM)
//   [134217728,150994944) vthi [4][1024][2048] (16 MiB)

#define GLOBAL_AS __attribute__((address_space(1)))
#define LDS_AS    __attribute__((address_space(3)))

typedef __attribute__((ext_vector_type(8))) short short8;
typedef __attribute__((ext_vector_type(4))) float f32x4;
typedef long long ll;

__device__ __forceinline__ unsigned short f2bf(float f) {
  unsigned u = __float_as_uint(f);
  u += 0x7FFFu + ((u >> 16) & 1u);   // RTNE (finite values only here)
  return (unsigned short)(u >> 16);
}
__device__ __forceinline__ float bf2f(unsigned short s) {
  return __uint_as_float((unsigned)s << 16);
}

__device__ __forceinline__ void gload_lds16(const unsigned short* g, unsigned short* l) {
  __builtin_amdgcn_global_load_lds((const GLOBAL_AS unsigned int*)g,
                                   (LDS_AS unsigned int*)l, 16, 0, 0);
}

// ---------------- fp32 -> (bf16 hi, bf16 lo) split conversion -----------------
__global__ __launch_bounds__(256) void split_f32_kernel(
    const float* __restrict__ src, unsigned short* __restrict__ hi,
    unsigned short* __restrict__ lo, int n8) {
  int i = blockIdx.x * 256 + threadIdx.x;
  if (i >= n8) return;
  const float4* s4 = (const float4*)src;
  float4 a = s4[2 * i], c = s4[2 * i + 1];
  float v[8] = {a.x, a.y, a.z, a.w, c.x, c.y, c.z, c.w};
  unsigned hw[4], lw[4];
#pragma unroll
  for (int j = 0; j < 4; ++j) {
    unsigned short h0 = f2bf(v[2 * j]),     h1 = f2bf(v[2 * j + 1]);
    unsigned short l0 = f2bf(v[2 * j] - bf2f(h0));
    unsigned short l1 = f2bf(v[2 * j + 1] - bf2f(h1));
    hw[j] = (unsigned)h0 | ((unsigned)h1 << 16);
    lw[j] = (unsigned)l0 | ((unsigned)l1 << 16);
  }
  *(uint4*)(hi + 8 * i) = make_uint4(hw[0], hw[1], hw[2], hw[3]);
  *(uint4*)(lo + 8 * i) = make_uint4(lw[0], lw[1], lw[2], lw[3]);
}

// --------------- 8-phase 256x256 A·B^T GEMM (m201 geometry) -------------------
// MODE 0 = qk projection: A=x(hi,lo), B={Wq|Wk}(hi,lo) by tj>>2; 3 passes;
//          split-bf16 out (q or k). grid (256,1), ntc=8.
// MODE 3 = v projection: A=xhi, B=Wv hi; 1 pass; vT bf16 out. grid (128,1), ntc=4.
// MODE 1 = S=q k^T causal: 3 passes; fp32 out; triangular 36-tile list. grid (36,4).
// MODE 2 = out=P vT^T: 1 pass; nkb=(ti+1)*4; fp32 out. grid (32,4), ntc=4.
template <int MODE>
__global__ __launch_bounds__(512, 2) void gemm8p(
    const unsigned short* __restrict__ A0, const unsigned short* __restrict__ A1,
    int lda, ll strA,
    const unsigned short* __restrict__ B0, const unsigned short* __restrict__ B1,
    const unsigned short* __restrict__ B2, const unsigned short* __restrict__ B3,
    int ldb, ll strB,
    void* __restrict__ C0, void* __restrict__ C1, void* __restrict__ C2,
    void* __restrict__ C3, ll strC, int ntc) {
  // 128 KiB: A dbuf 2x(256x64) | B dbuf 2x(256x64), bf16
  __shared__ __align__(16) unsigned short smA[2 * 16384];
  __shared__ __align__(16) unsigned short smB[2 * 16384];

  // m204 bijective XCD swizzle (works for any gridDim.x)
  const int nwg = gridDim.x, bx0 = blockIdx.x;
  const int q2 = nwg >> 3, r2 = nwg & 7, xcd = bx0 & 7;
  const int bx = (xcd < r2 ? xcd * (q2 + 1) : r2 * (q2 + 1) + (xcd - r2) * q2)
                 + (bx0 >> 3);
  const int b = blockIdx.y;

  int ti, tj;
  if constexpr (MODE == 1) {  // lower-triangular (ti,tj), tj<=ti, 36 tiles
    int rem = bx, i = 0;
    while (rem > i) { rem -= (i + 1); ++i; }
    ti = i; tj = rem;
  } else {
    ti = bx / ntc; tj = bx - ti * ntc;
  }
  const int row0 = ti << 8;

  const unsigned short *aH, *aL, *bH, *bL;
  int nkb, which = 0;
  if constexpr (MODE == 0) {
    which = tj >> 2;
    aH = A0 + (ll)row0 * lda; aL = A1 + (ll)row0 * lda;
    bH = (which ? B2 : B0) + (ll)((tj & 3) << 8) * ldb;
    bL = (which ? B3 : B1) + (ll)((tj & 3) << 8) * ldb;
    nkb = 48;
  } else if constexpr (MODE == 3) {
    aH = A0 + (ll)row0 * lda; aL = aH;
    bH = B0 + (ll)(tj << 8) * ldb; bL = bH;
    nkb = 16;
  } else if constexpr (MODE == 1) {
    aH = A0 + b * strA + (ll)row0 * lda; aL = A1 + b * strA + (ll)row0 * lda;
    bH = B0 + b * strB + (ll)(tj << 8) * ldb;
    bL = B1 + b * strB + (ll)(tj << 8) * ldb;
    nkb = 48;
  } else {  // MODE 2
    aH = A0 + b * strA + (ll)row0 * lda; aL = aH;
    bH = B0 + b * strB + (ll)(tj << 8) * ldb; bL = bH;
    nkb = (ti + 1) << 2;
  }

  const int t = threadIdx.x;
  const int lane = t & 63, w = t >> 6;
  const int wm = w >> 2, wn = w & 3;           // 2M x 4N waves
  const int fr = lane & 15, fg = lane >> 4;

  // staging maps: thread handles 4x16B chunks per 256x64 tile; source chunk
  // XOR-swizzled (rule #21: LDS dest linear, permute the GLOBAL source)
  int aoff[4], boff[4], dst4[4];
#pragma unroll
  for (int c = 0; c < 4; ++c) {
    const int lin = c * 512 + t, r = lin >> 3, jc = lin & 7;
    dst4[c] = lin << 3;
    aoff[c] = r * lda + ((jc ^ (r & 7)) << 3);
    boff[c] = r * ldb + ((jc ^ (r & 7)) << 3);
  }

  auto stageA = [&](int kb) {   // stage A-tile of virtual K-block kb
    int p, k0;
    if constexpr (MODE == 0 || MODE == 1) { p = kb >> 4; k0 = (kb & 15) << 6; }
    else { p = 0; k0 = kb << 6; }
    const unsigned short* pA = (p == 2) ? aL : aH;
    unsigned short* dst = smA + ((kb & 1) << 14);
#pragma unroll
    for (int c = 0; c < 4; ++c) gload_lds16(pA + (aoff[c] + k0), dst + dst4[c]);
  };
  auto stageB = [&](int kb, int half) {  // stage half of B-tile of kb
    int p, k0;
    if constexpr (MODE == 0 || MODE == 1) { p = kb >> 4; k0 = (kb & 15) << 6; }
    else { p = 0; k0 = kb << 6; }
    const unsigned short* pB = (p == 1) ? bL : bH;
    unsigned short* dst = smB + ((kb & 1) << 14);
#pragma unroll
    for (int c = 0; c < 2; ++c) {
      const int cc = half * 2 + c;
      gload_lds16(pB + (boff[cc] + k0), dst + dst4[cc]);
    }
  };

  f32x4 acc[8][4];
#pragma unroll
  for (int m = 0; m < 8; ++m)
#pragma unroll
    for (int n = 0; n < 4; ++n) acc[m][n] = (f32x4){0.f, 0.f, 0.f, 0.f};

  // ---- prologue: A0,B0 fully staged + B1 in flight; wait A0,B0 only ----
  stageA(0); stageB(0, 0); stageB(0, 1); stageB(1, 0); stageB(1, 1);
  asm volatile("s_waitcnt vmcnt(4)" ::: "memory");
  __builtin_amdgcn_s_barrier();

  for (int j = 0; j < nkb; ++j) {
    const int slot = j & 1;
    const unsigned short* LA = smA + (slot << 14);
    const unsigned short* LB = smB + (slot << 14);
    short8 bfrag[4][2];
#pragma unroll
    for (int mp = 0; mp < 4; ++mp) {   // 4 phases per K-tile
      // --- phase ds_reads (de-swizzle with same XOR) ---
      short8 af[2][2];
#pragma unroll
      for (int mi = 0; mi < 2; ++mi) {
        const int row = wm * 128 + (mp * 2 + mi) * 16 + fr;
#pragma unroll
        for (int ks = 0; ks < 2; ++ks)
          af[mi][ks] = *(const short8*)(LA + row * 64 + (((ks * 4 + fg) ^ (row & 7)) << 3));
      }
      if (mp == 0) {
#pragma unroll
        for (int n = 0; n < 4; ++n) {
          const int row = wn * 64 + n * 16 + fr;
#pragma unroll
          for (int ks = 0; ks < 2; ++ks)
            bfrag[n][ks] = *(const short8*)(LB + row * 64 + (((ks * 4 + fg) ^ (row & 7)) << 3));
        }
        if (j + 1 < nkb) stageA(j + 1);       // overwrites A(j-1): read-done
      }
      if (mp == 1 && j + 2 < nkb) stageB(j + 2, 0);  // overwrites B(j): read-done @p0
      if (mp == 2 && j + 2 < nkb) stageB(j + 2, 1);
      __builtin_amdgcn_s_barrier();
      __builtin_amdgcn_s_setprio(1);
#pragma unroll
      for (int ks = 0; ks < 2; ++ks)
#pragma unroll
        for (int n = 0; n < 4; ++n)
#pragma unroll
          for (int mi = 0; mi < 2; ++mi)
            acc[mp * 2 + mi][n] = __builtin_amdgcn_mfma_f32_16x16x32_bf16(
                af[mi][ks], bfrag[n][ks], acc[mp * 2 + mi][n], 0, 0, 0);
      __builtin_amdgcn_s_setprio(0);
      if (mp == 3) {  // one counted wait per K-tile; leaves B(j+2) in flight
        if (j + 2 < nkb)      asm volatile("s_waitcnt vmcnt(4)" ::: "memory");
        else if (j + 1 < nkb) asm volatile("s_waitcnt vmcnt(0)" ::: "memory");
      }
      __builtin_amdgcn_s_barrier();
    }
  }

  // ---- epilogue: D layout col=lane&15, row=(lane>>4)*4+jj [m89-verified] ----
#pragma unroll
  for (int m = 0; m < 8; ++m)
#pragma unroll
    for (int n = 0; n < 4; ++n)
#pragma unroll
      for (int jj = 0; jj < 4; ++jj) {
        const int r = row0 + wm * 128 + m * 16 + fg * 4 + jj;
        const int colin = wn * 64 + n * 16 + fr;
        const float v = acc[m][n][jj];
        if constexpr (MODE == 0) {
          unsigned short* hi = (unsigned short*)(which ? C2 : C0);
          unsigned short* lo = (unsigned short*)(which ? C3 : C1);
          const ll addr = (ll)r * 1024 + ((tj & 3) << 8) + colin;
          const unsigned short h = f2bf(v);
          hi[addr] = h;
          lo[addr] = f2bf(v - bf2f(h));
        } else if constexpr (MODE == 3) {  // vT[bb][d][tt]
          const int bb = r >> 11, tt = r & 2047;
          const int d = (tj << 8) + colin;
          ((unsigned short*)C0)[(ll)bb * (1024LL * 2048) + (ll)d * 2048 + tt] = f2bf(v);
        } else if constexpr (MODE == 1) {
          ((float*)C0)[b * strC + (ll)r * 2048 + (tj << 8) + colin] = v;
        } else {
          ((float*)C0)[b * strC + (ll)r * 1024 + (tj << 8) + colin] = v;
        }
      }
}

// ---------------- causal row softmax: S fp32 -> P bf16 (zero-filled) ----------
__global__ __launch_bounds__(256) void softmax_causal_kernel(
    const float* __restrict__ S, unsigned short* __restrict__ P) {
  __shared__ float red[8];
  const int tq = blockIdx.x;
  const int b = blockIdx.y;
  const float* s = S + (ll)b * 2048 * 2048 + (ll)tq * 2048;
  unsigned short* p = P + (ll)b * 2048 * 2048 + (ll)tq * 2048;
  const int n = tq + 1;
  const int t = threadIdx.x;

  float vals[8];
  float mx = -1e30f;
#pragma unroll
  for (int c = 0; c < 8; ++c) {
    const int i = t + c * 256;
    if (i < n) { vals[c] = s[i]; mx = fmaxf(mx, vals[c]); }
  }
#pragma unroll
  for (int o = 32; o > 0; o >>= 1) mx = fmaxf(mx, __shfl_xor(mx, o, 64));
  if ((t & 63) == 0) red[t >> 6] = mx;
  __syncthreads();
  mx = fmaxf(fmaxf(red[0], red[1]), fmaxf(red[2], red[3]));

  float sum = 0.f;
#pragma unroll
  for (int c = 0; c < 8; ++c) {
    const int i = t + c * 256;
    if (i < n) { const float e = __expf(vals[c] - mx); vals[c] = e; sum += e; }
  }
#pragma unroll
  for (int o = 32; o > 0; o >>= 1) sum += __shfl_xor(sum, o, 64);
  if ((t & 63) == 0) red[4 + (t >> 6)] = sum;
  __syncthreads();
  sum = (red[4] + red[5]) + (red[6] + red[7]);
  const float inv = 1.0f / sum;
#pragma unroll
  for (int c = 0; c < 8; ++c) {
    const int i = t + c * 256;
    if (i < n) p[i] = f2bf(vals[c] * inv);
  }
  for (int ii = t; ii < 2048; ii += 256)
    if (ii >= n) p[ii] = 0;  // zero-fill masked cols so PV reads are clean
}

// -------------------------------- launch --------------------------------------
extern "C" void kernel_launch(void* const* d_in, const int* in_sizes, int n_in,
                              void* d_out, int out_size, void* d_ws, size_t ws_size,
                              hipStream_t stream) {
  (void)in_sizes; (void)n_in; (void)out_size; (void)ws_size;
  const float* x  = (const float*)d_in[0];
  const float* Wk = (const float*)d_in[1];  // input order: x, Wk, Wq, Wv
  const float* Wq = (const float*)d_in[2];
  const float* Wv = (const float*)d_in[3];
  char* ws = (char*)d_ws;

  float*          Sbuf = (float*)ws;                              // 64 MiB
  unsigned short* wkhi = (unsigned short*)(ws + 0);
  unsigned short* wklo = (unsigned short*)(ws + 2097152);
  unsigned short* wqhi = (unsigned short*)(ws + 4194304);
  unsigned short* wqlo = (unsigned short*)(ws + 6291456);
  unsigned short* wvhi = (unsigned short*)(ws + 8388608);
  unsigned short* wvlo = (unsigned short*)(ws + 10485760);
  unsigned short* xhi  = (unsigned short*)(ws + 12582912);
  unsigned short* xlo  = (unsigned short*)(ws + 29360128);
  unsigned short* qhi  = (unsigned short*)(ws + 67108864);
  unsigned short* qlo  = (unsigned short*)(ws + 83886080);
  unsigned short* khi  = (unsigned short*)(ws + 100663296);
  unsigned short* klo  = (unsigned short*)(ws + 117440512);
  unsigned short* Pbuf = (unsigned short*)(ws + 67108864);        // overlays q
  unsigned short* vthi = (unsigned short*)(ws + 134217728);

  // 1) split conversions (Wv lo converted but unused)
  split_f32_kernel<<<4096, 256, 0, stream>>>(x, xhi, xlo, 1048576);
  split_f32_kernel<<<512, 256, 0, stream>>>(Wq, wqhi, wqlo, 131072);
  split_f32_kernel<<<512, 256, 0, stream>>>(Wk, wkhi, wklo, 131072);
  split_f32_kernel<<<512, 256, 0, stream>>>(Wv, wvhi, wvlo, 131072);

  // 2) q,k projections: 32 row-tiles x 8 col-tiles (4 q | 4 k) = 256 blocks
  gemm8p<0><<<dim3(256, 1), 512, 0, stream>>>(
      xhi, xlo, 1024, 0,
      wqhi, wqlo, wkhi, wklo, 1024, 0,
      qhi, qlo, khi, klo, 0, 8);

  // 3) v projection: 32 x 4 = 128 blocks, 1 pass -> vT
  gemm8p<3><<<dim3(128, 1), 512, 0, stream>>>(
      xhi, xhi, 1024, 0,
      wvhi, wvhi, nullptr, nullptr, 1024, 0,
      vthi, nullptr, nullptr, nullptr, 0, 4);

  // 4) S = q k^T, causal 256x256 tiles: 36 x 4 batches
  gemm8p<1><<<dim3(36, 4), 512, 0, stream>>>(
      qhi, qlo, 1024, 2048LL * 1024,
      khi, klo, nullptr, nullptr, 1024, 2048LL * 1024,
      Sbuf, nullptr, nullptr, nullptr, 2048LL * 2048, 8);

  // 5) causal softmax -> P (bf16, zero-filled above diagonal)
  softmax_causal_kernel<<<dim3(2048, 4), 256, 0, stream>>>(Sbuf, Pbuf);

  // 6) out = P vT^T: 8 row-tiles x 4 col-tiles, nkb=(ti+1)*4
  gemm8p<2><<<dim3(32, 4), 512, 0, stream>>>(
      Pbuf, Pbuf, 2048, 2048LL * 2048,
      vthi, vthi, nullptr, nullptr, 2048, 1024LL * 2048,
      d_out, nullptr, nullptr, nullptr, 2048LL * 1024, 4);
}